// Round 1
// baseline (778.239 us; speedup 1.0000x reference)
//
#include <hip/hip_runtime.h>

// ---------------------------------------------------------------------------
// out[b][o][12h+i][w] = sum_c x_i[b][c][h][w] * W[c][o] + bias[o]*count[12h+i]
// GEMM: M=393216 px, K=256, N=256. Memory-bound: 805 MB @6.3TB/s => ~128us.
// Rev: 16-wave blocks (4 waves/SIMD), XOR-swizzled LDS (conflict-free b128
// A-reads), lgkmcnt-only barriers (loads/stores stay in flight across them).
// ---------------------------------------------------------------------------

typedef __attribute__((ext_vector_type(8))) short bf16x8;
typedef __attribute__((ext_vector_type(4))) float f32x4;

#define ROW_B 512            // LDS row stride bytes: 256 ch * 2B
#define TILE_B (64 * ROW_B)  // 32 KB per buffer, 2 buffers = 64 KB

struct Ptrs12 { const float* p[12]; };

__device__ __forceinline__ unsigned f2bf1(float f) {
  unsigned u = __float_as_uint(f);
  return (u + 0x7FFFu + ((u >> 16) & 1u)) >> 16;   // RNE f32 -> bf16 bits
}

// Pre-swizzle W (fp32 [c][o]) into bf16 MFMA B-fragment order:
// Wf[u][s][lane][j], u = o-tile (0..15), s = k-step (0..7),
// lane: n = u*16 + (lane&15), k = s*32 + (lane>>4)*8 + j
__global__ void w_prepass(const float* __restrict__ W, unsigned short* __restrict__ Wf) {
  int idx = blockIdx.x * 256 + threadIdx.x;   // 65536 total
  int j = idx & 7, l = (idx >> 3) & 63, s = (idx >> 9) & 7, u = idx >> 12;
  int c = s * 32 + (l >> 4) * 8 + j;
  int o = u * 16 + (l & 15);
  Wf[idx] = (unsigned short)f2bf1(W[c * 256 + o]);
}

// Barrier with LDS-visibility only: do NOT drain vmcnt (T4). The only
// cross-wave state is LDS; global loads/stores keep flying across it.
#define LBAR() do {                                   \
  __builtin_amdgcn_sched_barrier(0);                  \
  asm volatile("s_waitcnt lgkmcnt(0)" ::: "memory");  \
  __builtin_amdgcn_s_barrier();                       \
  __builtin_amdgcn_sched_barrier(0);                  \
} while (0)

__global__ __launch_bounds__(1024, 4) void gemm12(Ptrs12 xs,
                                                  const unsigned short* __restrict__ Wf,
                                                  const float* __restrict__ bias,
                                                  float* __restrict__ out) {
  __shared__ char smem[2 * TILE_B];           // 64 KB double-buffered x tile
  const int tid = threadIdx.x;
  const int v = tid >> 6;                     // wave 0..15 (owns 16 N-outputs)
  const int l = tid & 63;
  const int q = l >> 4;                       // quad 0..3
  const int m = l & 15;

  // W fragments for this wave's 16 outputs, all K: 8 frags = 32 VGPRs.
  bf16x8 wf[8];
#pragma unroll
  for (int s = 0; s < 8; ++s)
    wf[s] = *(const bf16x8*)(Wf + (((v * 8 + s) * 64 + l) << 3));
  const float bv = bias[v * 16 + m];

  const int tile0 = blockIdx.x * 24;          // 256 blocks * 24 tiles = 6144
  float4 pf[4];                               // global prefetch regs (16 VGPR)

  // One 64px x 256ch tile: thread loads channels cb..cb+3 at w = w0+m*4..+3.
  auto tload = [&](int tile) {
    int row = tile >> 2, w0 = (tile & 3) << 6;
    int i = row >> 7, bb = (row >> 6) & 1, h = row & 63;
    const float* xp = xs.p[i] + (size_t)bb * 4194304 + h * 256 + w0 + m * 4;
    int cb = v * 16 + q * 4;
#pragma unroll
    for (int dc = 0; dc < 4; ++dc)
      pf[dc] = *(const float4*)(xp + (size_t)(cb + dc) * 16384);
  };
  // Convert + transpose into LDS [px][c] bf16, XOR-swizzled by pixel row so
  // the stride-512B fragment reads are bank-conflict-free.
  auto twrite = [&](int bs) {
    char* lb = smem + bs * TILE_B;
    const int col = v * 32 + q * 8;           // byte column = cb*2
#pragma unroll
    for (int k = 0; k < 4; ++k) {
      unsigned lo = f2bf1(((const float*)&pf[0])[k]) |
                    (f2bf1(((const float*)&pf[1])[k]) << 16);
      unsigned hi = f2bf1(((const float*)&pf[2])[k]) |
                    (f2bf1(((const float*)&pf[3])[k]) << 16);
      uint2 val; val.x = lo; val.y = hi;
      int row = m * 4 + k;
      unsigned a = (unsigned)(row * ROW_B + col) ^ ((unsigned)(row & 7) << 4);
      *(uint2*)(lb + a) = val;
    }
  };

  tload(tile0);
  twrite(0);
  LBAR();

#pragma unroll 1
  for (int mt = 0; mt < 24; ++mt) {
    const int tile = tile0 + mt;
    if (mt < 23) tload(tile + 1);             // issue next tile's global loads

    f32x4 acc[4];
#pragma unroll
    for (int z = 0; z < 4; ++z) acc[z] = 0.0f;

    const char* lb = smem + (mt & 1) * TILE_B;
#pragma unroll
    for (int s = 0; s < 8; ++s) {
      bf16x8 af[4];
#pragma unroll
      for (int m16 = 0; m16 < 4; ++m16) {     // A frag: px = m16*16+m, k = s*32+q*8+j
        int row = m16 * 16 + m;
        unsigned a = (unsigned)(row * ROW_B + s * 64 + q * 16) ^
                     ((unsigned)(row & 7) << 4);
        af[m16] = *(const bf16x8*)(lb + a);
      }
#pragma unroll
      for (int m16 = 0; m16 < 4; ++m16)
        acc[m16] = __builtin_amdgcn_mfma_f32_16x16x32_bf16(af[m16], wf[s], acc[m16], 0, 0, 0);
    }

    // Epilogue: bias*count + coalesced float4 stores (fire-and-forget; the
    // LBAR below does not wait for them).
    // C/D layout: col(o) = lane&15, row(px) = q*4 + reg -> 4 consecutive w.
    {
      int row = tile >> 2, w0 = (tile & 3) << 6;
      int i = row >> 7, bb = (row >> 6) & 1, h = row & 63;
      int r = h * 12 + i;
      int cnt_i = (r < 11 ? r : 11) - (r > 756 ? r - 756 : 0) + 1;
      float ba = bv * (float)cnt_i;
      float* op = out + (size_t)bb * 50331648u + (size_t)r * 256 + w0 + q * 4
                      + (size_t)(v * 16 + m) * 196608;
#pragma unroll
      for (int m16 = 0; m16 < 4; ++m16) {
        float4 sv;
        sv.x = acc[m16][0] + ba;
        sv.y = acc[m16][1] + ba;
        sv.z = acc[m16][2] + ba;
        sv.w = acc[m16][3] + ba;
        *(float4*)(op + m16 * 16) = sv;
      }
    }

    if (mt < 23) {
      twrite((mt + 1) & 1);                   // drain loads (counted vmcnt), ds_write
      LBAR();
    }
  }
}

extern "C" void kernel_launch(void* const* d_in, const int* in_sizes, int n_in,
                              void* d_out, int out_size, void* d_ws, size_t ws_size,
                              hipStream_t stream) {
  Ptrs12 xs;
  for (int i = 0; i < 12; ++i) xs.p[i] = (const float*)d_in[i];
  const float* W = (const float*)d_in[12];
  const float* bias = (const float*)d_in[13];
  unsigned short* Wf = (unsigned short*)d_ws;   // 128 KB bf16 swizzled W

  hipLaunchKernelGGL(w_prepass, dim3(256), dim3(256), 0, stream, W, Wf);
  hipLaunchKernelGGL(gemm12, dim3(256), dim3(1024), 0, stream, xs, Wf, bias, (float*)d_out);
}